// Round 1
// baseline (295.180 us; speedup 1.0000x reference)
//
#include <hip/hip_runtime.h>

#define N 4096
#define CIN 64
#define CQ 8
#define NB 2

// workspace layout (float offsets)
#define OFF_QT 0
#define OFF_KT (OFF_QT + NB*N*8)
#define OFF_JT (OFF_KT + NB*N*8)
#define OFF_V  (OFF_JT + NB*N*8)
#define OFF_KK (OFF_V + NB*CIN*N)
#define OFF_KJ (OFF_KK + NB*N*8)
#define OFF_MX (OFF_KJ + NB*64)
#define OFF_SC (OFF_MX + NB*N)

// ---------------- prep: q,k,j projections (depthwise-3 convs over one axis) ---
// grid (16, 24, 2) block 256; y = type*8+cq
__global__ void prep_qkj(const float* __restrict__ x,
                         const float* __restrict__ wq, const float* __restrict__ bq,
                         const float* __restrict__ wk, const float* __restrict__ bk,
                         const float* __restrict__ wj, const float* __restrict__ bj,
                         float* __restrict__ ws) {
    int n  = blockIdx.x * 256 + threadIdx.x;
    int tc = blockIdx.y;
    int b  = blockIdx.z;
    int type = tc >> 3, cq = tc & 7;
    const float *w, *bias;
    float* outp;
    int delta, coord;
    if (type == 0)      { w = wq; bias = bq; outp = ws + OFF_QT; delta = 16;  coord = (n >> 4) & 15; }
    else if (type == 1) { w = wk; bias = bk; outp = ws + OFF_KT; delta = 256; coord = n >> 8; }
    else                { w = wj; bias = bj; outp = ws + OFF_JT; delta = 1;   coord = n & 15; }
    const float* xb = x + b * (CIN * N) + n;
    const float* wr = w + cq * CIN * 3;
    float acc = bias[cq];
    bool lo = coord > 0, hi = coord < 15;
#pragma unroll 8
    for (int c = 0; c < CIN; ++c) {
        const float* p = xb + c * N;
        float w0 = wr[c * 3 + 0], w1 = wr[c * 3 + 1], w2 = wr[c * 3 + 2];
        if (lo) acc += w0 * p[-delta];
        acc += w1 * p[0];
        if (hi) acc += w2 * p[delta];
    }
    outp[(b * N + n) * 8 + cq] = acc;
}

// ---------------- prep: v = 1x1x1 conv; also out = x ------------------------
// grid (16, 64, 2) block 256
__global__ void prep_v(const float* __restrict__ x, const float* __restrict__ wv,
                       const float* __restrict__ bv, float* __restrict__ out,
                       float* __restrict__ ws) {
    int n  = blockIdx.x * 256 + threadIdx.x;
    int co = blockIdx.y;
    int b  = blockIdx.z;
    const float* xb = x + b * CIN * N + n;
    const float* wr = wv + co * CIN;
    float acc = bv[co];
#pragma unroll 8
    for (int c = 0; c < CIN; ++c) acc += wr[c] * xb[c * N];
    ws[OFF_V + (b * CIN + co) * N + n] = acc;
    out[(b * CIN + co) * N + n] = xb[co * N];   // init out = x
}

// ---------------- kj[b][c][d] = sum_n k[c,n] j[d,n] -------------------------
// grid (16, 2) block 256; kj must be pre-zeroed
__global__ void kj_reduce(const float* __restrict__ ws, float* __restrict__ kj) {
    int b = blockIdx.y;
    int n = blockIdx.x * 256 + threadIdx.x;
    const float4* kt = (const float4*)(ws + OFF_KT + (b * N + n) * 8);
    const float4* jt = (const float4*)(ws + OFF_JT + (b * N + n) * 8);
    float4 ka = kt[0], kb = kt[1], ja = jt[0], jb = jt[1];
    float kv[8] = {ka.x, ka.y, ka.z, ka.w, kb.x, kb.y, kb.z, kb.w};
    float jv[8] = {ja.x, ja.y, ja.z, ja.w, jb.x, jb.y, jb.z, jb.w};
    float acc[64];
#pragma unroll
    for (int c = 0; c < 8; ++c)
#pragma unroll
        for (int d = 0; d < 8; ++d) acc[c * 8 + d] = kv[c] * jv[d];
#pragma unroll
    for (int s = 32; s >= 1; s >>= 1)
#pragma unroll
        for (int i = 0; i < 64; ++i) acc[i] += __shfl_down(acc[i], s, 64);
    if ((threadIdx.x & 63) == 0) {
#pragma unroll
        for (int i = 0; i < 64; ++i) atomicAdd(&kj[b * 64 + i], acc[i]);
    }
}

// ---------------- kkT[b][m][c] = sum_d kj[c][d] * k[d][m] -------------------
// grid (16, 2) block 256
__global__ void kk_kernel(const float* __restrict__ ws_in, const float* __restrict__ kjg,
                          float* __restrict__ ws) {
    int b = blockIdx.y;
    int m = blockIdx.x * 256 + threadIdx.x;
    float kjv[64];
#pragma unroll
    for (int i = 0; i < 64; ++i) kjv[i] = kjg[b * 64 + i];
    const float4* kt = (const float4*)(ws_in + OFF_KT + (b * N + m) * 8);
    float4 ka = kt[0], kb = kt[1];
    float kv[8] = {ka.x, ka.y, ka.z, ka.w, kb.x, kb.y, kb.z, kb.w};
    float o[8];
#pragma unroll
    for (int c = 0; c < 8; ++c) {
        float a = 0.f;
#pragma unroll
        for (int d = 0; d < 8; ++d) a += kjv[c * 8 + d] * kv[d];
        o[c] = a;
    }
    float4* dst = (float4*)(ws + OFF_KK + (b * N + m) * 8);
    dst[0] = make_float4(o[0], o[1], o[2], o[3]);
    dst[1] = make_float4(o[4], o[5], o[6], o[7]);
}

// ---------------- pass1: row softmax stats (max & gamma/sum) ----------------
// grid 512 block 256; wave handles 4 rows, lanes split m
__global__ __launch_bounds__(256) void pass1(const float* __restrict__ ws,
                                             float* __restrict__ mx_o, float* __restrict__ sc_o,
                                             const float* __restrict__ gamma) {
    int wid = threadIdx.x >> 6, lane = threadIdx.x & 63;
    int gw = blockIdx.x * 4 + wid;       // 0..2047
    int r0 = gw * 4;                     // 4 rows
    int b = r0 >> 12;
    float4 qa[4], qb[4];
#pragma unroll
    for (int rr = 0; rr < 4; ++rr) {
        const float4* q4 = (const float4*)(ws + OFF_QT + (size_t)(r0 + rr) * 8);
        qa[rr] = q4[0]; qb[rr] = q4[1];
    }
    const float* kkb = ws + OFF_KK + (size_t)b * N * 8;
    float mx[4], sm[4];
#pragma unroll
    for (int rr = 0; rr < 4; ++rr) { mx[rr] = -3.0e38f; sm[rr] = 0.f; }
#pragma unroll 4
    for (int i = 0; i < 64; ++i) {
        int m = i * 64 + lane;
        const float4* kk4 = (const float4*)(kkb + m * 8);
        float4 ka = kk4[0], kb = kk4[1];
#pragma unroll
        for (int rr = 0; rr < 4; ++rr) {
            float a = qa[rr].x * ka.x + qa[rr].y * ka.y + qa[rr].z * ka.z + qa[rr].w * ka.w
                    + qb[rr].x * kb.x + qb[rr].y * kb.y + qb[rr].z * kb.z + qb[rr].w * kb.w;
            float nm = fmaxf(mx[rr], a);
            sm[rr] = sm[rr] * __expf(mx[rr] - nm) + __expf(a - nm);
            mx[rr] = nm;
        }
    }
#pragma unroll
    for (int s = 32; s >= 1; s >>= 1)
#pragma unroll
        for (int rr = 0; rr < 4; ++rr) {
            float omx = __shfl_xor(mx[rr], s, 64);
            float osm = __shfl_xor(sm[rr], s, 64);
            float nm = fmaxf(mx[rr], omx);
            sm[rr] = sm[rr] * __expf(mx[rr] - nm) + osm * __expf(omx - nm);
            mx[rr] = nm;
        }
    if (lane == 0) {
        float g = gamma[0];
#pragma unroll
        for (int rr = 0; rr < 4; ++rr) {
            mx_o[r0 + rr] = mx[rr];
            sc_o[r0 + rr] = g / sm[rr];
        }
    }
}

// ---------------- pass2: out += gamma * V . softmax(aff) --------------------
// grid (64, 4, 2) block 256: x = m-tile(64), y = n-slice(1024), z = b
__global__ __launch_bounds__(256) void pass2(const float* __restrict__ ws, float* __restrict__ out) {
    __shared__ float Pt[64][68];   // [mi][nl]  stride 68: reads/writes <=2-way
    __shared__ float Vt[64][68];   // [c][nl]
    int t = threadIdx.x;
    int b = blockIdx.z;
    int m0 = blockIdx.x * 64;
    int ns = blockIdx.y;
    const float* qT  = ws + OFF_QT + (size_t)b * N * 8;
    const float* kkT = ws + OFF_KK + (size_t)b * N * 8;
    const float* vb  = ws + OFF_V + (size_t)b * CIN * N;
    const float* mxv = ws + OFF_MX + (size_t)b * N;
    const float* scv = ws + OFF_SC + (size_t)b * N;

    int lane_mi = t & 15;     // thread's m set: {lane_mi + 16k}
    int lane_c  = t >> 4;     // thread's c set: {lane_c + 16k}
    int lane64 = t & 63;
    int quad = t >> 6;
    float acc[4][4];
#pragma unroll
    for (int i = 0; i < 4; ++i)
#pragma unroll
        for (int j = 0; j < 4; ++j) acc[i][j] = 0.f;

    for (int tile = 0; tile < 16; ++tile) {
        int n0 = ns * 1024 + tile * 64;
        int n = n0 + lane64;
        // stage P: lanes = nl (coalesced q reads, conflict-free LDS writes)
        const float4* q4 = (const float4*)(qT + (size_t)n * 8);
        float4 qa = q4[0], qb = q4[1];
        float mxl = mxv[n];
#pragma unroll
        for (int r = 0; r < 16; ++r) {
            int mi = quad * 16 + r;
            const float4* kk4 = (const float4*)(kkT + (size_t)(m0 + mi) * 8);
            float4 ka = kk4[0], kb = kk4[1];
            float a = qa.x * ka.x + qa.y * ka.y + qa.z * ka.z + qa.w * ka.w
                    + qb.x * kb.x + qb.y * kb.y + qb.z * kb.z + qb.w * kb.w;
            Pt[mi][lane64] = __expf(a - mxl);
        }
        // stage V * (gamma/rowsum[n])
        float s = scv[n];
#pragma unroll
        for (int r = 0; r < 16; ++r) {
            int c = quad * 16 + r;
            Vt[c][lane64] = vb[(size_t)c * N + n] * s;
        }
        __syncthreads();
        // 64x64x64 tile product, 4c x 4m per thread, float4 along n
        for (int i = 0; i < 16; ++i) {
            float4 pv[4], vv[4];
#pragma unroll
            for (int k = 0; k < 4; ++k) pv[k] = *(const float4*)&Pt[lane_mi + 16 * k][4 * i];
#pragma unroll
            for (int k = 0; k < 4; ++k) vv[k] = *(const float4*)&Vt[lane_c + 16 * k][4 * i];
#pragma unroll
            for (int kc = 0; kc < 4; ++kc)
#pragma unroll
                for (int km = 0; km < 4; ++km)
                    acc[kc][km] += vv[kc].x * pv[km].x + vv[kc].y * pv[km].y
                                 + vv[kc].z * pv[km].z + vv[kc].w * pv[km].w;
        }
        __syncthreads();
    }
    float* ob = out + (size_t)b * CIN * N;
#pragma unroll
    for (int kc = 0; kc < 4; ++kc) {
        int c = lane_c + 16 * kc;
#pragma unroll
        for (int km = 0; km < 4; ++km) {
            int m = m0 + lane_mi + 16 * km;
            atomicAdd(&ob[(size_t)c * N + m], acc[kc][km]);
        }
    }
}

extern "C" void kernel_launch(void* const* d_in, const int* in_sizes, int n_in,
                              void* d_out, int out_size, void* d_ws, size_t ws_size,
                              hipStream_t stream) {
    const float* x  = (const float*)d_in[0];
    const float* wq = (const float*)d_in[1];
    const float* bq = (const float*)d_in[2];
    const float* wk = (const float*)d_in[3];
    const float* bk = (const float*)d_in[4];
    const float* wj = (const float*)d_in[5];
    const float* bj = (const float*)d_in[6];
    const float* wv = (const float*)d_in[7];
    const float* bv = (const float*)d_in[8];
    const float* gamma = (const float*)d_in[9];
    float* ws  = (float*)d_ws;
    float* out = (float*)d_out;

    hipMemsetAsync(ws + OFF_KJ, 0, NB * 64 * sizeof(float), stream);
    prep_qkj<<<dim3(16, 24, 2), 256, 0, stream>>>(x, wq, bq, wk, bk, wj, bj, ws);
    prep_v<<<dim3(16, 64, 2), 256, 0, stream>>>(x, wv, bv, out, ws);
    kj_reduce<<<dim3(16, 2), 256, 0, stream>>>(ws, ws + OFF_KJ);
    kk_kernel<<<dim3(16, 2), 256, 0, stream>>>(ws, ws + OFF_KJ, ws);
    pass1<<<512, 256, 0, stream>>>(ws, ws + OFF_MX, ws + OFF_SC, gamma);
    pass2<<<dim3(64, 4, 2), 256, 0, stream>>>(ws, out);
}

// Round 2
// 227.161 us; speedup vs baseline: 1.2994x; 1.2994x over previous
//
#include <hip/hip_runtime.h>

#define N 4096
#define CIN 64
#define NB 2

typedef unsigned short u16;
typedef short bf16x8 __attribute__((ext_vector_type(8)));
typedef float f32x4 __attribute__((ext_vector_type(4)));

// workspace layout (float offsets). OFF_V region is reused as bf16 (u16) storage.
#define OFF_QT 0
#define OFF_KT (OFF_QT + NB*N*8)
#define OFF_JT (OFF_KT + NB*N*8)
#define OFF_V  (OFF_JT + NB*N*8)
#define OFF_KK (OFF_V + NB*CIN*N)
#define OFF_KJ (OFF_KK + NB*N*8)
#define OFF_MX (OFF_KJ + NB*64)
#define OFF_SC (OFF_MX + NB*N)

__device__ __forceinline__ u16 f2bf(float f) {
    union { float f; unsigned u; } v; v.f = f;
    unsigned r = (v.u + 0x7fffu + ((v.u >> 16) & 1u)) >> 16;  // RNE
    return (u16)r;
}

// ---------------- prep: q,k,j projections (3-tap convs over one axis) -------
// grid (16, 24, 2) block 256; y = type*8+cq
__global__ void prep_qkj(const float* __restrict__ x,
                         const float* __restrict__ wq, const float* __restrict__ bq,
                         const float* __restrict__ wk, const float* __restrict__ bk,
                         const float* __restrict__ wj, const float* __restrict__ bj,
                         float* __restrict__ ws) {
    int n  = blockIdx.x * 256 + threadIdx.x;
    int tc = blockIdx.y;
    int b  = blockIdx.z;
    int type = tc >> 3, cq = tc & 7;
    const float *w, *bias;
    float* outp;
    int delta, coord;
    if (type == 0)      { w = wq; bias = bq; outp = ws + OFF_QT; delta = 16;  coord = (n >> 4) & 15; }
    else if (type == 1) { w = wk; bias = bk; outp = ws + OFF_KT; delta = 256; coord = n >> 8; }
    else                { w = wj; bias = bj; outp = ws + OFF_JT; delta = 1;   coord = n & 15; }
    const float* xb = x + b * (CIN * N) + n;
    const float* wr = w + cq * CIN * 3;
    float acc = bias[cq];
    bool lo = coord > 0, hi = coord < 15;
#pragma unroll 8
    for (int c = 0; c < CIN; ++c) {
        const float* p = xb + c * N;
        float w0 = wr[c * 3 + 0], w1 = wr[c * 3 + 1], w2 = wr[c * 3 + 2];
        if (lo) acc += w0 * p[-delta];
        acc += w1 * p[0];
        if (hi) acc += w2 * p[delta];
    }
    outp[(b * N + n) * 8 + cq] = acc;
}

// ---------------- prep: v = 1x1x1 conv (bf16 out); also out = x -------------
// grid (16, 64, 2) block 256
__global__ void prep_v(const float* __restrict__ x, const float* __restrict__ wv,
                       const float* __restrict__ bv, float* __restrict__ out,
                       u16* __restrict__ vbf) {
    int n  = blockIdx.x * 256 + threadIdx.x;
    int co = blockIdx.y;
    int b  = blockIdx.z;
    const float* xb = x + b * CIN * N + n;
    const float* wr = wv + co * CIN;
    float acc = bv[co];
#pragma unroll 8
    for (int c = 0; c < CIN; ++c) acc += wr[c] * xb[c * N];
    vbf[(size_t)(b * CIN + co) * N + n] = f2bf(acc);
    out[(b * CIN + co) * N + n] = xb[co * N];   // init out = x
}

// ---------------- kj[b][c][d] = sum_n k[c,n] j[d,n] -------------------------
// grid (16, 2) block 256; kj must be pre-zeroed
__global__ void kj_reduce(const float* __restrict__ ws, float* __restrict__ kj) {
    int b = blockIdx.y;
    int n = blockIdx.x * 256 + threadIdx.x;
    const float4* kt = (const float4*)(ws + OFF_KT + (b * N + n) * 8);
    const float4* jt = (const float4*)(ws + OFF_JT + (b * N + n) * 8);
    float4 ka = kt[0], kb = kt[1], ja = jt[0], jb = jt[1];
    float kv[8] = {ka.x, ka.y, ka.z, ka.w, kb.x, kb.y, kb.z, kb.w};
    float jv[8] = {ja.x, ja.y, ja.z, ja.w, jb.x, jb.y, jb.z, jb.w};
    float acc[64];
#pragma unroll
    for (int c = 0; c < 8; ++c)
#pragma unroll
        for (int d = 0; d < 8; ++d) acc[c * 8 + d] = kv[c] * jv[d];
#pragma unroll
    for (int s = 32; s >= 1; s >>= 1)
#pragma unroll
        for (int i = 0; i < 64; ++i) acc[i] += __shfl_down(acc[i], s, 64);
    if ((threadIdx.x & 63) == 0) {
#pragma unroll
        for (int i = 0; i < 64; ++i) atomicAdd(&kj[b * 64 + i], acc[i]);
    }
}

// ---------------- kkT[b][m][c] = sum_d kj[c][d] * k[d][m] -------------------
// grid (16, 2) block 256
__global__ void kk_kernel(const float* __restrict__ ws_in, const float* __restrict__ kjg,
                          float* __restrict__ ws) {
    int b = blockIdx.y;
    int m = blockIdx.x * 256 + threadIdx.x;
    float kjv[64];
#pragma unroll
    for (int i = 0; i < 64; ++i) kjv[i] = kjg[b * 64 + i];
    const float4* kt = (const float4*)(ws_in + OFF_KT + (b * N + m) * 8);
    float4 ka = kt[0], kb = kt[1];
    float kv[8] = {ka.x, ka.y, ka.z, ka.w, kb.x, kb.y, kb.z, kb.w};
    float o[8];
#pragma unroll
    for (int c = 0; c < 8; ++c) {
        float a = 0.f;
#pragma unroll
        for (int d = 0; d < 8; ++d) a += kjv[c * 8 + d] * kv[d];
        o[c] = a;
    }
    float4* dst = (float4*)(ws + OFF_KK + (b * N + m) * 8);
    dst[0] = make_float4(o[0], o[1], o[2], o[3]);
    dst[1] = make_float4(o[4], o[5], o[6], o[7]);
}

// ---------------- pass1: row softmax stats (max & gamma/sum) ----------------
// grid 512 block 256; wave handles 4 rows, lanes split m
__global__ __launch_bounds__(256) void pass1(const float* __restrict__ ws,
                                             float* __restrict__ mx_o, float* __restrict__ sc_o,
                                             const float* __restrict__ gamma) {
    int wid = threadIdx.x >> 6, lane = threadIdx.x & 63;
    int gw = blockIdx.x * 4 + wid;
    int r0 = gw * 4;
    int b = r0 >> 12;
    float4 qa[4], qb[4];
#pragma unroll
    for (int rr = 0; rr < 4; ++rr) {
        const float4* q4 = (const float4*)(ws + OFF_QT + (size_t)(r0 + rr) * 8);
        qa[rr] = q4[0]; qb[rr] = q4[1];
    }
    const float* kkb = ws + OFF_KK + (size_t)b * N * 8;
    float mx[4], sm[4];
#pragma unroll
    for (int rr = 0; rr < 4; ++rr) { mx[rr] = -3.0e38f; sm[rr] = 0.f; }
#pragma unroll 4
    for (int i = 0; i < 64; ++i) {
        int m = i * 64 + lane;
        const float4* kk4 = (const float4*)(kkb + m * 8);
        float4 ka = kk4[0], kb = kk4[1];
#pragma unroll
        for (int rr = 0; rr < 4; ++rr) {
            float a = qa[rr].x * ka.x + qa[rr].y * ka.y + qa[rr].z * ka.z + qa[rr].w * ka.w
                    + qb[rr].x * kb.x + qb[rr].y * kb.y + qb[rr].z * kb.z + qb[rr].w * kb.w;
            float nm = fmaxf(mx[rr], a);
            sm[rr] = sm[rr] * __expf(mx[rr] - nm) + __expf(a - nm);
            mx[rr] = nm;
        }
    }
#pragma unroll
    for (int s = 32; s >= 1; s >>= 1)
#pragma unroll
        for (int rr = 0; rr < 4; ++rr) {
            float omx = __shfl_xor(mx[rr], s, 64);
            float osm = __shfl_xor(sm[rr], s, 64);
            float nm = fmaxf(mx[rr], omx);
            sm[rr] = sm[rr] * __expf(mx[rr] - nm) + osm * __expf(omx - nm);
            mx[rr] = nm;
        }
    if (lane == 0) {
        float g = gamma[0];
#pragma unroll
        for (int rr = 0; rr < 4; ++rr) {
            mx_o[r0 + rr] = mx[rr];
            sc_o[r0 + rr] = g / sm[rr];
        }
    }
}

// ---------------- pass2: out += V_bf16 . (sc*exp(aff-mx))_bf16 via MFMA -----
// grid (64, 8, 2) block 256: x = m-tile(64), y = n-slice(512), z = b
// LDS layout [row][k-contig] stride 72 (16B-aligned rows, b128 frag reads).
__global__ __launch_bounds__(256) void pass2(const float* __restrict__ ws,
                                             const u16* __restrict__ vbf,
                                             float* __restrict__ out) {
    __shared__ u16 Pt[64][72];      // P' tile: [m][n]  (B-frag: B[k=n][col=m])
    __shared__ u16 Vt[64][72];      // V tile:  [c][n]  (A-frag: A[row=c][k=n])
    __shared__ float kks[64][8];    // kk for this m-tile
    const int t  = threadIdx.x;
    const int b  = blockIdx.z;
    const int m0 = blockIdx.x * 64;
    const int ns = blockIdx.y;
    const float* qT  = ws + OFF_QT + (size_t)b * N * 8;
    const float* kkT = ws + OFF_KK + (size_t)b * N * 8;
    const float* mxv = ws + OFF_MX + (size_t)b * N;
    const float* scv = ws + OFF_SC + (size_t)b * N;
    const u16*   vb  = vbf + (size_t)b * CIN * N;

    if (t < 128) ((float4*)kks)[t] = ((const float4*)(kkT + (size_t)m0 * 8))[t];

    const int lane = t & 63;
    const int wid  = t >> 6;        // wave id -> m-subtile
    const int l16  = lane & 15;
    const int lq   = lane >> 4;     // lane quad -> k-octet / acc row group
    const int vc   = t >> 3;        // V staging row 0..31
    const int vseg = t & 7;

    f32x4 acc[4];
#pragma unroll
    for (int i = 0; i < 4; ++i) acc[i] = (f32x4){0.f, 0.f, 0.f, 0.f};

    for (int ch = 0; ch < 8; ++ch) {
        const int n0 = ns * 512 + ch * 64;
        const int n  = n0 + lane;
        const float4* q4 = (const float4*)(qT + (size_t)n * 8);
        float4 qa = q4[0], qb = q4[1];
        float mxl = mxv[n], sl = scv[n];
        uint4 v0 = *(const uint4*)(vb + (size_t)vc        * N + n0 + vseg * 8);
        uint4 v1 = *(const uint4*)(vb + (size_t)(vc + 32) * N + n0 + vseg * 8);
        __syncthreads();            // prev chunk's MFMA reads done (chunk 0: kks staged)
#pragma unroll
        for (int r = 0; r < 16; ++r) {
            int mi = wid * 16 + r;
            float4 k0 = *(const float4*)&kks[mi][0];   // broadcast (uniform per wave)
            float4 k1 = *(const float4*)&kks[mi][4];
            float a = qa.x * k0.x + qa.y * k0.y + qa.z * k0.z + qa.w * k0.w
                    + qb.x * k1.x + qb.y * k1.y + qb.z * k1.z + qb.w * k1.w;
            Pt[mi][lane] = f2bf(__expf(a - mxl) * sl);  // fold gamma/rowsum into P
        }
        *(uint4*)&Vt[vc][vseg * 8]      = v0;
        *(uint4*)&Vt[vc + 32][vseg * 8] = v1;
        __syncthreads();
#pragma unroll
        for (int ks = 0; ks < 2; ++ks) {
            int k0i = ks * 32 + lq * 8;
            bf16x8 bfrag = *(const bf16x8*)&Pt[wid * 16 + l16][k0i];
#pragma unroll
            for (int ct = 0; ct < 4; ++ct) {
                bf16x8 afrag = *(const bf16x8*)&Vt[ct * 16 + l16][k0i];
                acc[ct] = __builtin_amdgcn_mfma_f32_16x16x32_bf16(afrag, bfrag, acc[ct], 0, 0, 0);
            }
        }
    }
    // D layout: col(=m) = lane&15, row(=c within tile) = lq*4 + reg
    float* ob = out + (size_t)b * CIN * N;
    const int mcol = m0 + wid * 16 + l16;
#pragma unroll
    for (int ct = 0; ct < 4; ++ct)
#pragma unroll
        for (int r = 0; r < 4; ++r) {
            int c = ct * 16 + lq * 4 + r;
            atomicAdd(&ob[(size_t)c * N + mcol], acc[ct][r]);
        }
}

extern "C" void kernel_launch(void* const* d_in, const int* in_sizes, int n_in,
                              void* d_out, int out_size, void* d_ws, size_t ws_size,
                              hipStream_t stream) {
    const float* x  = (const float*)d_in[0];
    const float* wq = (const float*)d_in[1];
    const float* bq = (const float*)d_in[2];
    const float* wk = (const float*)d_in[3];
    const float* bk = (const float*)d_in[4];
    const float* wj = (const float*)d_in[5];
    const float* bj = (const float*)d_in[6];
    const float* wv = (const float*)d_in[7];
    const float* bv = (const float*)d_in[8];
    const float* gamma = (const float*)d_in[9];
    float* ws  = (float*)d_ws;
    float* out = (float*)d_out;
    u16* vbf = (u16*)(ws + OFF_V);

    hipMemsetAsync(ws + OFF_KJ, 0, NB * 64 * sizeof(float), stream);
    prep_qkj<<<dim3(16, 24, 2), 256, 0, stream>>>(x, wq, bq, wk, bk, wj, bj, ws);
    prep_v<<<dim3(16, 64, 2), 256, 0, stream>>>(x, wv, bv, out, vbf);
    kj_reduce<<<dim3(16, 2), 256, 0, stream>>>(ws, ws + OFF_KJ);
    kk_kernel<<<dim3(16, 2), 256, 0, stream>>>(ws, ws + OFF_KJ, ws);
    pass1<<<512, 256, 0, stream>>>(ws, ws + OFF_MX, ws + OFF_SC, gamma);
    pass2<<<dim3(64, 8, 2), 256, 0, stream>>>(ws, vbf, out);
}